// Round 4
// baseline (923.700 us; speedup 1.0000x reference)
//
#include <hip/hip_runtime.h>

// SoftMorphology soft-skeleton: columns-in-registers, shuffle-based stencil.
//
//   erode(x) = min over 5-pt cross; open = dilate3x3(erode); 11 erosions,
//   skel = relu(img-open(img)); 10x: skel += relu(d - skel*d), d=relu(E-open(E)).
//
// Layout: 64-thread blocks (1 wave). Wave owns 256 cols (4/lane, float4),
// R rows per lane in registers f[R]. Vertical neighbors = register-local;
// horizontal = 2 shuffles/row. grid.x=5 waves tile W=1024 with disjoint
// quad-aligned write windows (52,52,52,52,48 quads); read windows overlap
// by >= halo. Zero LDS, zero barriers.
//
// Per stage one in-place ascending pass: at iteration i,
//   e = erode(old f[i-1..i+1]) -> stored to f[i-1] (window shifts up 1/stage);
//   h0 = hmax3(e) (rolling h2,h1,h0 = new rows i-3,i-2,i-1);
//   update for skel row j=i-2 (new-idx): dilate = vmax3(h2,h1,h0),
//   A_{t-1} at that row == pm1 (saved before overwrite).
//
// Borders: staged loads clamp row/col (guards = replicate). For EROSION,
// guards >= true-extension are absorbed by min (center term dominates;
// induction holds every stage) -- no re-replication needed. DILATE needs
// exact extension: per-lane overrides at image cols 0/1023 (cndmask) and
// h-row swap at image rows 0/1023 (block-uniform).

#define W 1024
#define H 1024
#define NBATCH 16
#define RV 16

__device__ __forceinline__ float min3f(float a, float b, float c) {
  return fminf(fminf(a, b), c);
}
__device__ __forceinline__ float max3f(float a, float b, float c) {
  return fmaxf(fmaxf(a, b), c);
}

template <int STAGES, bool FIRST>
__global__ __launch_bounds__(64, 2) void skel_pass(
    const float* __restrict__ in,   // img (FIRST) or E6
    float* __restrict__ e_out,      // E6 out (FIRST only)
    float* __restrict__ skel) {
  constexpr int HALO = STAGES + 1;
  constexpr int R = RV + 2 * HALO;

  const int l = threadIdx.x;
  const int w = blockIdx.x;                 // 0..4 column windows
  const int y0 = blockIdx.y * RV;
  const size_t base = (size_t)blockIdx.z * (size_t)(W * H);

  const int rx = 208 * w - 8 + 4 * l;       // lane's col start (may be OOB)
  const int cq = min(max(rx, 0), W - 4);    // clamped load col
  const bool mL = (rx == 0);                // lane's c0 is image col 0
  const bool mR = (rx == W - 4);            // lane's c3 is image col 1023
  const bool top = (y0 == 0);
  const bool bot = (y0 + RV == H);
  const int wend = min(208 * (w + 1), W);
  const bool wr = (rx >= 208 * w) && (rx < wend);

  // ---- stage input rows (row/col clamped) ----
  float4 f[R];
#pragma unroll
  for (int i = 0; i < R; ++i) {
    const int gy = min(max(y0 - HALO + i, 0), H - 1);
    f[i] = *(const float4*)(in + base + (size_t)gy * W + cq);
  }

  float4 sk[RV];
  if (!FIRST) {
#pragma unroll
    for (int k = 0; k < RV; ++k)
      sk[k] = *(const float4*)(skel + base + (size_t)(y0 + k) * W + cq);
  }

#pragma unroll
  for (int t = 1; t <= STAGES; ++t) {
    const int V = R - 2 * (t - 1);          // valid rows at stage entry
    float4 pm1 = f[0];
    float4 h0, h1, h2;
#pragma unroll
    for (int i = 1; i <= V - 2; ++i) {
      const float4 cur = f[i];
      const float4 nxt = f[i + 1];
      // erode: vertical min3 then cross with horizontal neighbors
      float4 e;
      const float vmx = min3f(pm1.x, cur.x, nxt.x);
      const float vmy = min3f(pm1.y, cur.y, nxt.y);
      const float vmz = min3f(pm1.z, cur.z, nxt.z);
      const float vmw = min3f(pm1.w, cur.w, nxt.w);
      float Lin = __shfl_up(cur.w, 1, 64);
      if (mL) Lin = cur.x;                  // image col 0: ext == center
      float Rin = __shfl_down(cur.x, 1, 64);
      if (mR) Rin = cur.w;                  // image col 1023
      e.x = min3f(vmx, Lin, cur.y);
      e.y = min3f(vmy, cur.x, cur.z);
      e.z = min3f(vmz, cur.y, cur.w);
      e.w = min3f(vmw, cur.z, Rin);
      f[i - 1] = e;                         // in-place, window shifts up

      // h = hmax3(e) for new-row m=i-1, needed for m in [jlo-1, jhi+1]
      if (i >= HALO - t && i <= HALO - t + RV + 1) {
        float Lh = __shfl_up(e.w, 1, 64);
        if (mL) Lh = e.x;
        float Rh = __shfl_down(e.x, 1, 64);
        if (mR) Rh = e.w;
        h0.x = max3f(Lh, e.x, e.y);
        h0.y = max3f(e.x, e.y, e.z);
        h0.z = max3f(e.y, e.z, e.w);
        h0.w = max3f(e.z, e.w, Rh);
      }
      // update for skel row k: new-idx center j=i-2; pm1 == A_{t-1} there
      if (i >= HALO - t + 2 && i <= HALO - t + RV + 1) {
        const int k = i - 2 - (HALO - t);
        float4 ha = h2, hb = h0;
        if (k == 0 && top) ha = h1;         // image row 0: ext == center
        if (k == RV - 1 && bot) hb = h1;    // image row 1023
        float4 dd, dl;
        dd.x = max3f(ha.x, h1.x, hb.x);
        dd.y = max3f(ha.y, h1.y, hb.y);
        dd.z = max3f(ha.z, h1.z, hb.z);
        dd.w = max3f(ha.w, h1.w, hb.w);
        dl.x = fmaxf(pm1.x - dd.x, 0.f);
        dl.y = fmaxf(pm1.y - dd.y, 0.f);
        dl.z = fmaxf(pm1.z - dd.z, 0.f);
        dl.w = fmaxf(pm1.w - dd.w, 0.f);
        if (FIRST && t == 1) {
          sk[k] = dl;
        } else {
          sk[k].x += fmaxf(dl.x - sk[k].x * dl.x, 0.f);
          sk[k].y += fmaxf(dl.y - sk[k].y * dl.y, 0.f);
          sk[k].z += fmaxf(dl.z - sk[k].z * dl.z, 0.f);
          sk[k].w += fmaxf(dl.w - sk[k].w * dl.w, 0.f);
        }
      }
      h2 = h1;
      h1 = h0;
      pm1 = cur;
    }
  }

  // ---- stores: write lanes only (disjoint quad-aligned windows) ----
  if (wr) {
#pragma unroll
    for (int k = 0; k < RV; ++k)
      *(float4*)(skel + base + (size_t)(y0 + k) * W + rx) = sk[k];
    if (FIRST) {
#pragma unroll
      for (int k = 0; k < RV; ++k)
        *(float4*)(e_out + base + (size_t)(y0 + k) * W + rx) = f[1 + k];
    }
  }
}

extern "C" void kernel_launch(void* const* d_in, const int* in_sizes, int n_in,
                              void* d_out, int out_size, void* d_ws,
                              size_t ws_size, hipStream_t stream) {
  const float* img = (const float*)d_in[0];
  float* skel = (float*)d_out;
  float* E = (float*)d_ws;  // 64 MiB: E6 between the two launches

  dim3 grid(5, H / RV, NBATCH);
  // Launch 1: stages 1..6 = skel init + iters 1..5; writes E6 + skel.
  skel_pass<6, true><<<grid, 64, 0, stream>>>(img, E, skel);
  // Launch 2: stages 7..11 = iters 6..10; reads E6 + skel, writes skel.
  skel_pass<5, false><<<grid, 64, 0, stream>>>(E, nullptr, skel);
}

// Round 5
// 277.659 us; speedup vs baseline: 3.3267x; 3.3267x over previous
//
#include <hip/hip_runtime.h>

// SoftMorphology soft-skeleton: columns-in-registers, shuffle-based stencil.
// Round-5: same verified algorithm as round 4, but split 11 stages over
// THREE launches (4+4+3) so the register window fits without spilling:
//   halo = STAGES+1 = 5,5,4 ; R = RV + 2*halo = 18,18,16 rows/lane (float4)
//   f[18]*4 = 72 VGPR + sk[8]*4 = 32 + temps ~= 145 << 256 cap.
// (Round-4 bug: 2 launches -> R=30 -> ~280 VGPR demand -> allocator spill
//  mode at 128 VGPR -> 1.15 GB scratch traffic per dispatch.)
//
// Layout: 64-thread blocks (1 wave). Wave owns 256 cols (4/lane, float4),
// R rows per lane in registers. Vertical neighbors = register-local;
// horizontal = 2 shuffles/row. grid.x=5 waves tile W=1024 with disjoint
// quad-aligned write windows (208,208,208,208,192 cols); read windows
// overlap by >= halo+contamination margin. Zero LDS, zero barriers.
//
// Per stage one in-place ascending pass: at iteration i,
//   e = erode(old f[i-1..i+1]) -> f[i-1] (window shifts up 1/stage);
//   h0 = hmax3(e) rolling (h2,h1,h0 = new rows i-3,i-2,i-1);
//   update for row j=i-2 (new-idx): dilate = vmax3(h2,h1,h0),
//   A_{t-1} there == pm1 (saved before overwrite).
// Stage t in launch starting at E_s computes iter k = s + t - 1:
//   delta_k = relu(E_k - dilate(E_{k+1})), E_k = A_{t-1}, E_{k+1} = A_t.
//
// Borders: staged loads clamp row/col (guards = replicate). For EROSION,
// replicate guards >= true extension are absorbed by the min (center term
// dominates; induction holds each stage). DILATE needs exact extension:
// per-lane overrides at image cols 0/1023 (cndmask) and h-row swap at
// image rows 0/1023.

#define W 1024
#define H 1024
#define NBATCH 16
#define RV 8

__device__ __forceinline__ float min3f(float a, float b, float c) {
  return fminf(fminf(a, b), c);
}
__device__ __forceinline__ float max3f(float a, float b, float c) {
  return fmaxf(fmaxf(a, b), c);
}

template <int STAGES, bool FIRST, bool EOUT>
__global__ __launch_bounds__(64, 2) void skel_pass(
    const float* __restrict__ in,   // E_s  (img when FIRST)
    float* __restrict__ e_out,      // E_{s+STAGES} out (EOUT only)
    float* __restrict__ skel) {
  constexpr int HALO = STAGES + 1;
  constexpr int R = RV + 2 * HALO;

  const int l = threadIdx.x;
  const int w = blockIdx.x;                 // 0..4 column windows
  const int y0 = blockIdx.y * RV;
  const size_t base = (size_t)blockIdx.z * (size_t)(W * H);

  const int rx = 208 * w - 8 + 4 * l;       // lane's col start (may be OOB)
  const int cq = min(max(rx, 0), W - 4);    // clamped load col
  const bool mL = (rx == 0);                // lane's c0 is image col 0
  const bool mR = (rx == W - 4);            // lane's c3 is image col 1023
  const bool top = (y0 == 0);
  const bool bot = (y0 + RV == H);
  const int wend = min(208 * (w + 1), W);
  const bool wr = (rx >= 208 * w) && (rx < wend);

  // ---- stage input rows (row/col clamped) ----
  float4 f[R];
#pragma unroll
  for (int i = 0; i < R; ++i) {
    const int gy = min(max(y0 - HALO + i, 0), H - 1);
    f[i] = *(const float4*)(in + base + (size_t)gy * W + cq);
  }

  float4 sk[RV];
  if (!FIRST) {
#pragma unroll
    for (int k = 0; k < RV; ++k)
      sk[k] = *(const float4*)(skel + base + (size_t)(y0 + k) * W + cq);
  }

#pragma unroll
  for (int t = 1; t <= STAGES; ++t) {
    const int V = R - 2 * (t - 1);          // valid rows at stage entry
    float4 pm1 = f[0];
    float4 h0, h1, h2;
#pragma unroll
    for (int i = 1; i <= V - 2; ++i) {
      const float4 cur = f[i];
      const float4 nxt = f[i + 1];
      // erode: vertical min3 then cross with horizontal neighbors
      float4 e;
      const float vmx = min3f(pm1.x, cur.x, nxt.x);
      const float vmy = min3f(pm1.y, cur.y, nxt.y);
      const float vmz = min3f(pm1.z, cur.z, nxt.z);
      const float vmw = min3f(pm1.w, cur.w, nxt.w);
      float Lin = __shfl_up(cur.w, 1, 64);
      if (mL) Lin = cur.x;                  // image col 0: ext == center
      float Rin = __shfl_down(cur.x, 1, 64);
      if (mR) Rin = cur.w;                  // image col 1023
      e.x = min3f(vmx, Lin, cur.y);
      e.y = min3f(vmy, cur.x, cur.z);
      e.z = min3f(vmz, cur.y, cur.w);
      e.w = min3f(vmw, cur.z, Rin);
      f[i - 1] = e;                         // in-place, window shifts up

      // h = hmax3(e) for new-row m=i-1, needed for m in [jlo-1, jhi+1]
      if (i >= HALO - t && i <= HALO - t + RV + 1) {
        float Lh = __shfl_up(e.w, 1, 64);
        if (mL) Lh = e.x;
        float Rh = __shfl_down(e.x, 1, 64);
        if (mR) Rh = e.w;
        h0.x = max3f(Lh, e.x, e.y);
        h0.y = max3f(e.x, e.y, e.z);
        h0.z = max3f(e.y, e.z, e.w);
        h0.w = max3f(e.z, e.w, Rh);
      }
      // update for skel row k: new-idx center j=i-2; pm1 == A_{t-1} there
      if (i >= HALO - t + 2 && i <= HALO - t + RV + 1) {
        const int k = i - 2 - (HALO - t);
        float4 ha = h2, hb = h0;
        if (k == 0 && top) ha = h1;         // image row 0: ext == center
        if (k == RV - 1 && bot) hb = h1;    // image row 1023
        float4 dd, dl;
        dd.x = max3f(ha.x, h1.x, hb.x);
        dd.y = max3f(ha.y, h1.y, hb.y);
        dd.z = max3f(ha.z, h1.z, hb.z);
        dd.w = max3f(ha.w, h1.w, hb.w);
        dl.x = fmaxf(pm1.x - dd.x, 0.f);
        dl.y = fmaxf(pm1.y - dd.y, 0.f);
        dl.z = fmaxf(pm1.z - dd.z, 0.f);
        dl.w = fmaxf(pm1.w - dd.w, 0.f);
        if (FIRST && t == 1) {
          sk[k] = dl;
        } else {
          sk[k].x += fmaxf(dl.x - sk[k].x * dl.x, 0.f);
          sk[k].y += fmaxf(dl.y - sk[k].y * dl.y, 0.f);
          sk[k].z += fmaxf(dl.z - sk[k].z * dl.z, 0.f);
          sk[k].w += fmaxf(dl.w - sk[k].w * dl.w, 0.f);
        }
      }
      h2 = h1;
      h1 = h0;
      pm1 = cur;
    }
  }

  // ---- stores: write lanes only (disjoint quad-aligned windows) ----
  if (wr) {
#pragma unroll
    for (int k = 0; k < RV; ++k)
      *(float4*)(skel + base + (size_t)(y0 + k) * W + rx) = sk[k];
    if (EOUT) {
      // after STAGES stages, row y0+k is f[HALO - STAGES + k] = f[1 + k]
#pragma unroll
      for (int k = 0; k < RV; ++k)
        *(float4*)(e_out + base + (size_t)(y0 + k) * W + rx) = f[1 + k];
    }
  }
}

extern "C" void kernel_launch(void* const* d_in, const int* in_sizes, int n_in,
                              void* d_out, int out_size, void* d_ws,
                              size_t ws_size, hipStream_t stream) {
  const float* img = (const float*)d_in[0];
  float* skel = (float*)d_out;
  const size_t NPIX = (size_t)NBATCH * W * H;
  float* A = (float*)d_ws;        // E4
  float* B = A + NPIX;            // E8   (ws: 128 MiB)

  dim3 grid(5, H / RV, NBATCH);
  // L1: k=0 init + iters 1..3; reads img, writes E4 + skel.
  skel_pass<4, true, true><<<grid, 64, 0, stream>>>(img, A, skel);
  // L2: iters 4..7; reads E4 + skel, writes E8 + skel.
  skel_pass<4, false, true><<<grid, 64, 0, stream>>>(A, B, skel);
  // L3: iters 8..10; reads E8 + skel, writes skel.
  skel_pass<3, false, false><<<grid, 64, 0, stream>>>(B, B, skel);
}